// Round 3
// baseline (1862.285 us; speedup 1.0000x reference)
//
#include <hip/hip_runtime.h>

// RoiAlign (TF crop_and_resize, bilinear, extrapolation_value=0)
// boxes: [B, N, 4] f32 pixel coords (x1, y1, x2, y2)
// fpn:   [B, H, W, C] f32 (NHWC, C innermost)
// out:   [B, N, 14, 14, C] f32
//
// R1/R2: nt output stores (keep fpn L3-resident).              ~150 us kernel
// R3 (FAILED): fused prefetch blocks — no ordering, raced.      174 us
// R4 (FAILED): serialized warm pass — gather unchanged, +82 us.
//   Lesson: L3 residency does NOT speed the gather; scattered 1 KB request
//   service (~6-7 TB/s through fabric/L3) is the wall, and it applies to
//   L3 hits as much as HBM misses.
// R5: band binning. Counting-sort the 200704 positions by (image, 8-row
//   source band) so dispatch order has temporal locality: all accesses to
//   a 2 MB band happen together -> the 3.2x cross-box re-reads become
//   per-XCD L2 hits (34 TB/s) instead of scattered L3/HBM service, and the
//   compulsory 268 MB HBM fetch becomes a quasi-sequential band sweep.
//   Gather numerics identical to R2; only the schedule changes.
constexpr int CROP_H = 14;
constexpr int CROP_W = 14;
constexpr int B = 4, N = 256, H = 256, W = 256, C = 256;
constexpr int C4 = C / 4;                       // float4 per pixel
constexpr int POSITIONS = B * N * CROP_H * CROP_W;   // 200704
constexpr int NBANDS = 32;                      // 8-row bands (2 MB each)
constexpr int NBINS = B * NBANDS;               // 128
// ws layout (uint32 units): [0:128) counts | [128:256) cursors |
//                           [256:384) offsets | [512:512+POSITIONS) perm
constexpr size_t WS_PERM_OFF = 512;
constexpr size_t WS_NEEDED_BYTES = (WS_PERM_OFF + (size_t)POSITIONS) * 4;

typedef float vfloat4 __attribute__((ext_vector_type(4)));

// Shared position->source-row math. EXACT fp sequence of the reference.
__device__ inline int src_row_band(const float* __restrict__ boxes, int pos) {
  int t = pos / CROP_W;           // drop j
  int i = t % CROP_H;
  t /= CROP_H;
  int n = t % N;
  int b = t / N;
  const float* bx = boxes + (size_t)(b * N + n) * 4;
  float y1 = bx[1], y2 = bx[3];
  const float Hf = (float)H;
  float ny1 = y1 / Hf * Hf / (Hf - 1.0f);
  float ny2 = (y2 / Hf * Hf - 1.0f) / (Hf - 1.0f);
  float ty = (float)i / (float)(CROP_H - 1);
  float ys = (ny1 + (ny2 - ny1) * ty) * (Hf - 1.0f);
  float y0f = floorf(ys);
  int y0 = (int)fminf(fmaxf(y0f, 0.0f), Hf - 1.0f);
  return b * NBANDS + (y0 >> 3);  // bin
}

// K0: zero counts + cursors.
__global__ void k0_zero(unsigned int* __restrict__ ws) {
  ws[threadIdx.x] = 0u;           // 256 threads zero counts[128]+cursors[128]
}

// K1: histogram bins.
__global__ __launch_bounds__(256) void k1_count(
    const float* __restrict__ boxes, unsigned int* __restrict__ ws) {
  int pos = blockIdx.x * 256 + threadIdx.x;
  int bin = src_row_band(boxes, pos);
  atomicAdd(&ws[bin], 1u);
}

// K1b: exclusive scan of counts[128] -> offsets (single wave, serial).
__global__ void k1b_scan(unsigned int* __restrict__ ws) {
  if (threadIdx.x == 0) {
    unsigned int acc = 0;
    for (int i = 0; i < NBINS; ++i) {
      ws[256 + i] = acc;          // offsets
      acc += ws[i];               // counts
    }
  }
}

// K2: scatter position ids into bin-grouped perm (order within bin: atomic).
__global__ __launch_bounds__(256) void k2_scatter(
    const float* __restrict__ boxes, unsigned int* __restrict__ ws) {
  int pos = blockIdx.x * 256 + threadIdx.x;
  int bin = src_row_band(boxes, pos);
  unsigned int slot = ws[256 + bin] + atomicAdd(&ws[128 + bin], 1u);
  ws[WS_PERM_OFF + slot] = (unsigned int)pos;
}

// K3: gather in banded order. Body identical numerics to R2.
template <bool USE_PERM>
__global__ __launch_bounds__(256) void roi_align_kernel(
    const float* __restrict__ boxes,
    const float* __restrict__ fpn,
    float* __restrict__ out,
    const unsigned int* __restrict__ perm) {
  const int wave = threadIdx.x >> 6;
  const int lane = threadIdx.x & 63;
  const int slot = blockIdx.x * 4 + wave;       // [0, POSITIONS)
  const int pos = USE_PERM ? (int)perm[slot] : slot;

  int j = pos % CROP_W;
  int t = pos / CROP_W;
  int i = t % CROP_H;
  t /= CROP_H;
  int n = t % N;
  int b = t / N;

  const float* bx = boxes + (size_t)(b * N + n) * 4;
  float x1 = bx[0], y1 = bx[1], x2 = bx[2], y2 = bx[3];

  // Replicate the reference's exact fp32 normalization sequence.
  const float Hf = (float)H, Wf = (float)W;
  float ny1 = y1 / Hf * Hf / (Hf - 1.0f);
  float nx1 = x1 / Wf * Wf / (Wf - 1.0f);
  float ny2 = (y2 / Hf * Hf - 1.0f) / (Hf - 1.0f);
  float nx2 = (x2 / Wf * Wf - 1.0f) / (Wf - 1.0f);

  float ty = (float)i / (float)(CROP_H - 1);
  float tx = (float)j / (float)(CROP_W - 1);
  float ys = (ny1 + (ny2 - ny1) * ty) * (Hf - 1.0f);
  float xs = (nx1 + (nx2 - nx1) * tx) * (Wf - 1.0f);

  bool valid = (ys >= 0.0f) && (ys <= Hf - 1.0f) &&
               (xs >= 0.0f) && (xs <= Wf - 1.0f);

  float y0f = floorf(ys), x0f = floorf(xs);
  float wy = ys - y0f, wx = xs - x0f;
  int y0  = (int)fminf(fmaxf(y0f,        0.0f), Hf - 1.0f);
  int y1i = (int)fminf(fmaxf(y0f + 1.0f, 0.0f), Hf - 1.0f);
  int x0  = (int)fminf(fmaxf(x0f,        0.0f), Wf - 1.0f);
  int x1i = (int)fminf(fmaxf(x0f + 1.0f, 0.0f), Wf - 1.0f);

  const float4* f4 = (const float4*)fpn;
  int rb = b * H;
  size_t i00 = (size_t)((rb + y0)  * W + x0)  * C4 + lane;
  size_t i01 = (size_t)((rb + y0)  * W + x1i) * C4 + lane;
  size_t i10 = (size_t)((rb + y1i) * W + x0)  * C4 + lane;
  size_t i11 = (size_t)((rb + y1i) * W + x1i) * C4 + lane;

  float4 tl = f4[i00];
  float4 tr = f4[i01];
  float4 bl = f4[i10];
  float4 br = f4[i11];

  float w00 = (1.0f - wy) * (1.0f - wx);
  float w01 = (1.0f - wy) * wx;
  float w10 = wy * (1.0f - wx);
  float w11 = wy * wx;

  vfloat4 o;
  o.x = tl.x * w00 + tr.x * w01 + bl.x * w10 + br.x * w11;
  o.y = tl.y * w00 + tr.y * w01 + bl.y * w10 + br.y * w11;
  o.z = tl.z * w00 + tr.z * w01 + bl.z * w10 + br.z * w11;
  o.w = tl.w * w00 + tr.w * w01 + bl.w * w10 + br.w * w11;
  if (!valid) { o.x = 0.0f; o.y = 0.0f; o.z = 0.0f; o.w = 0.0f; }

  // Non-temporal store: the 205 MB output stream has no reuse.
  vfloat4* dst = (vfloat4*)out + (size_t)pos * C4 + lane;
  __builtin_nontemporal_store(o, dst);
}

extern "C" void kernel_launch(void* const* d_in, const int* in_sizes, int n_in,
                              void* d_out, int out_size, void* d_ws, size_t ws_size,
                              hipStream_t stream) {
  const float* boxes = (const float*)d_in[0];  // [B, N, 4]
  const float* fpn   = (const float*)d_in[1];  // [B, H, W, C]
  float* out = (float*)d_out;                  // [B, N, 14, 14, C]

  if (d_ws != nullptr && ws_size >= WS_NEEDED_BYTES) {
    unsigned int* ws = (unsigned int*)d_ws;
    hipLaunchKernelGGL(k0_zero,    dim3(1),              dim3(256), 0, stream, ws);
    hipLaunchKernelGGL(k1_count,   dim3(POSITIONS/256),  dim3(256), 0, stream, boxes, ws);
    hipLaunchKernelGGL(k1b_scan,   dim3(1),              dim3(64),  0, stream, ws);
    hipLaunchKernelGGL(k2_scatter, dim3(POSITIONS/256),  dim3(256), 0, stream, boxes, ws);
    hipLaunchKernelGGL(roi_align_kernel<true>, dim3(POSITIONS/4), dim3(256), 0,
                       stream, boxes, fpn, out, ws + WS_PERM_OFF);
  } else {
    // Workspace too small: fall back to the verified R2 schedule.
    hipLaunchKernelGGL(roi_align_kernel<false>, dim3(POSITIONS/4), dim3(256), 0,
                       stream, boxes, fpn, out, (const unsigned int*)nullptr);
  }
}

// Round 4
// 430.711 us; speedup vs baseline: 4.3237x; 4.3237x over previous
//
#include <hip/hip_runtime.h>

// RoiAlign (TF crop_and_resize, bilinear, extrapolation_value=0)
// boxes: [B, N, 4] f32 pixel coords (x1, y1, x2, y2)
// fpn:   [B, H, W, C] f32 (NHWC, C innermost)
// out:   [B, N, 14, 14, C] f32
//
// Journal:
// R1/R2: nt output stores.                               kernel ~150 us
// R3 (FAILED): fused prefetch — raced the gather.        174 us
// R4 (FAILED): serialized warm pass — gather unchanged.  +82 us
// R5 (FAILED): 200704 GLOBAL atomics on 128 bins = 800 us/kernel serial chain.
// Model (R5 post-mortem): R2 already services 1027 MB issued (822 rd + 205 wr)
//   in 150 us = 6.85 TB/s — AT the fabric/L3/HBM ceiling. L3 vs HBM residency
//   is irrelevant (R4); the fabric is the wall. Only lever: serve the 3.2x
//   re-reads from per-XCD L2 (34 TB/s), cutting fabric to 268 compulsory
//   + 205 write = 473 MB ~ 70 us.
// R6: (a) sort box-rows (14336 items) by (image, source row y0) in ONE
//   1024-thread block: LDS histogram (1024 bins) + shfl scan + LDS-atomic
//   scatter — no global atomics, ~15 us. (b) XCD-partition the sorted
//   stream: block g -> xcd = g%8 (HW round-robin mapping, m157-verified)
//   owns a contiguous 1/8 of sorted positions, so each source row is read
//   by exactly one XCD and the per-XCD in-flight window (~6 rows ~1.6 MB)
//   fits its private 4 MB L2. Gather numerics identical to R2.
constexpr int CROP_H = 14;
constexpr int CROP_W = 14;
constexpr int B = 4, N = 256, H = 256, W = 256, C = 256;
constexpr int C4 = C / 4;                          // float4 per pixel
constexpr int POSITIONS = B * N * CROP_H * CROP_W; // 200704
constexpr int NBOXES = B * N;                      // 1024
constexpr int ITEMS = NBOXES * CROP_H;             // 14336 box-rows
constexpr int NBINS = B * H;                       // 1024 (image, row)
constexpr int NXCD = 8;
constexpr int POS_PER_XCD = POSITIONS / NXCD;      // 25088
constexpr size_t WS_NEEDED_BYTES = (size_t)ITEMS * 4;

typedef float vfloat4 __attribute__((ext_vector_type(4)));

// ---- Launch 1: counting-sort box-rows by (image, y0 source row). ----
// Single block, 1024 threads; thread t owns box t (its 14 crop rows).
// All contention is on LDS (fast); no global atomics (R5 lesson).
__global__ __launch_bounds__(1024) void sort_rows_kernel(
    const float* __restrict__ boxes, unsigned int* __restrict__ perm) {
  __shared__ unsigned int cnt[NBINS];   // counts -> cursors
  __shared__ unsigned int wsum[16];     // per-wave scan partials
  const int tid = threadIdx.x;          // == box id, [0, 1024)
  cnt[tid] = 0u;
  __syncthreads();

  // EXACT reference fp sequence for the y path (same y0 as the gather).
  const float* bx = boxes + (size_t)tid * 4;
  const float y1 = bx[1], y2 = bx[3];
  const float Hf = (float)H;
  const float ny1 = y1 / Hf * Hf / (Hf - 1.0f);
  const float ny2 = (y2 / Hf * Hf - 1.0f) / (Hf - 1.0f);
  const int bimg = tid >> 8;

  unsigned int mybin[CROP_H];
#pragma unroll
  for (int i = 0; i < CROP_H; ++i) {
    float ty = (float)i / (float)(CROP_H - 1);
    float ys = (ny1 + (ny2 - ny1) * ty) * (Hf - 1.0f);
    float y0f = floorf(ys);
    int y0 = (int)fminf(fmaxf(y0f, 0.0f), Hf - 1.0f);
    mybin[i] = ((unsigned)bimg << 8) | (unsigned)y0;
    atomicAdd(&cnt[mybin[i]], 1u);      // LDS atomic
  }
  __syncthreads();

  // Exclusive scan of cnt[1024]: wave shfl-scan + 16 wave-total fixup.
  unsigned c0 = cnt[tid];
  unsigned v = c0;
#pragma unroll
  for (int d = 1; d < 64; d <<= 1) {
    unsigned u = __shfl_up(v, d);
    if ((tid & 63) >= d) v += u;
  }
  if ((tid & 63) == 63) wsum[tid >> 6] = v;
  __syncthreads();
  if (tid == 0) {
    unsigned acc = 0;
    for (int w = 0; w < 16; ++w) { unsigned t = wsum[w]; wsum[w] = acc; acc += t; }
  }
  __syncthreads();
  cnt[tid] = v - c0 + wsum[tid >> 6];   // bin start cursor
  __syncthreads();

  // Scatter item ids grouped by bin (order within bin arbitrary — it's a
  // permutation; every output position is still written exactly once).
#pragma unroll
  for (int i = 0; i < CROP_H; ++i) {
    unsigned slot = atomicAdd(&cnt[mybin[i]], 1u);  // LDS atomic
    perm[slot] = (unsigned)(tid * CROP_H + i);
  }
}

// ---- Launch 2: gather. Body identical numerics to R2 (absmax-preserving). ----
template <bool USE_PERM>
__global__ __launch_bounds__(256) void roi_align_kernel(
    const float* __restrict__ boxes,
    const float* __restrict__ fpn,
    float* __restrict__ out,
    const unsigned int* __restrict__ perm) {
  const int wave = threadIdx.x >> 6;
  const int lane = threadIdx.x & 63;

  int pos;
  if (USE_PERM) {
    // XCD x (blockIdx % 8, HW round-robin) owns sorted slots
    // [x*25088, (x+1)*25088): contiguous band sweep per XCD.
    const int xcd = blockIdx.x & 7;
    const int r   = blockIdx.x >> 3;
    const unsigned slot = (unsigned)(xcd * POS_PER_XCD + r * 4 + wave);
    const unsigned it = slot / 14u;          // sorted item index
    const unsigned jj = slot - it * 14u;     // j within the box-row
    pos = (int)(perm[it] * 14u + jj);
  } else {
    pos = blockIdx.x * 4 + wave;
  }

  int j = pos % CROP_W;
  int t = pos / CROP_W;
  int i = t % CROP_H;
  t /= CROP_H;
  int n = t % N;
  int b = t / N;

  const float* bx = boxes + (size_t)(b * N + n) * 4;
  float x1 = bx[0], y1 = bx[1], x2 = bx[2], y2 = bx[3];

  // Replicate the reference's exact fp32 normalization sequence.
  const float Hf = (float)H, Wf = (float)W;
  float ny1 = y1 / Hf * Hf / (Hf - 1.0f);
  float nx1 = x1 / Wf * Wf / (Wf - 1.0f);
  float ny2 = (y2 / Hf * Hf - 1.0f) / (Hf - 1.0f);
  float nx2 = (x2 / Wf * Wf - 1.0f) / (Wf - 1.0f);

  float ty = (float)i / (float)(CROP_H - 1);
  float tx = (float)j / (float)(CROP_W - 1);
  float ys = (ny1 + (ny2 - ny1) * ty) * (Hf - 1.0f);
  float xs = (nx1 + (nx2 - nx1) * tx) * (Wf - 1.0f);

  bool valid = (ys >= 0.0f) && (ys <= Hf - 1.0f) &&
               (xs >= 0.0f) && (xs <= Wf - 1.0f);

  float y0f = floorf(ys), x0f = floorf(xs);
  float wy = ys - y0f, wx = xs - x0f;
  int y0  = (int)fminf(fmaxf(y0f,        0.0f), Hf - 1.0f);
  int y1i = (int)fminf(fmaxf(y0f + 1.0f, 0.0f), Hf - 1.0f);
  int x0  = (int)fminf(fmaxf(x0f,        0.0f), Wf - 1.0f);
  int x1i = (int)fminf(fmaxf(x0f + 1.0f, 0.0f), Wf - 1.0f);

  const float4* f4 = (const float4*)fpn;
  int rb = b * H;
  size_t i00 = (size_t)((rb + y0)  * W + x0)  * C4 + lane;
  size_t i01 = (size_t)((rb + y0)  * W + x1i) * C4 + lane;
  size_t i10 = (size_t)((rb + y1i) * W + x0)  * C4 + lane;
  size_t i11 = (size_t)((rb + y1i) * W + x1i) * C4 + lane;

  float4 tl = f4[i00];
  float4 tr = f4[i01];
  float4 bl = f4[i10];
  float4 br = f4[i11];

  float w00 = (1.0f - wy) * (1.0f - wx);
  float w01 = (1.0f - wy) * wx;
  float w10 = wy * (1.0f - wx);
  float w11 = wy * wx;

  vfloat4 o;
  o.x = tl.x * w00 + tr.x * w01 + bl.x * w10 + br.x * w11;
  o.y = tl.y * w00 + tr.y * w01 + bl.y * w10 + br.y * w11;
  o.z = tl.z * w00 + tr.z * w01 + bl.z * w10 + br.z * w11;
  o.w = tl.w * w00 + tr.w * w01 + bl.w * w10 + br.w * w11;
  if (!valid) { o.x = 0.0f; o.y = 0.0f; o.z = 0.0f; o.w = 0.0f; }

  // nt store: the 205 MB output stream has no reuse — keep it out of L2/L3.
  vfloat4* dst = (vfloat4*)out + (size_t)pos * C4 + lane;
  __builtin_nontemporal_store(o, dst);
}

extern "C" void kernel_launch(void* const* d_in, const int* in_sizes, int n_in,
                              void* d_out, int out_size, void* d_ws, size_t ws_size,
                              hipStream_t stream) {
  const float* boxes = (const float*)d_in[0];  // [B, N, 4]
  const float* fpn   = (const float*)d_in[1];  // [B, H, W, C]
  float* out = (float*)d_out;                  // [B, N, 14, 14, C]

  if (d_ws != nullptr && ws_size >= WS_NEEDED_BYTES) {
    unsigned int* perm = (unsigned int*)d_ws;
    hipLaunchKernelGGL(sort_rows_kernel, dim3(1), dim3(1024), 0, stream,
                       boxes, perm);
    hipLaunchKernelGGL(roi_align_kernel<true>, dim3(POSITIONS / 4), dim3(256),
                       0, stream, boxes, fpn, out, perm);
  } else {
    // Workspace too small: fall back to the verified R2 schedule.
    hipLaunchKernelGGL(roi_align_kernel<false>, dim3(POSITIONS / 4), dim3(256),
                       0, stream, boxes, fpn, out, (const unsigned int*)nullptr);
  }
}